// Round 1
// baseline (223.011 us; speedup 1.0000x reference)
//
#include <hip/hip_runtime.h>
#include <stdint.h>

#define L_SEQ 2048
#define D_MODEL 1024
#define NHEAD 16
#define HS 64
#define B_BATCH 2
// 1/sqrt(64) * log2(e), folded into q at QKV epilogue (softmax in exp2 domain)
#define QSCALE 0.1803368801111243f

typedef __bf16 bf16x8 __attribute__((ext_vector_type(8)));
typedef float f32x4 __attribute__((ext_vector_type(4)));

__device__ __forceinline__ float fexp2(float x) {
  return __builtin_amdgcn_exp2f(x);  // v_exp_f32: D = 2^S0
}

__device__ __forceinline__ unsigned short f2b(float f) {
  unsigned int u = __float_as_uint(f);
  u += 0x7fffu + ((u >> 16) & 1u);
  return (unsigned short)(u >> 16);
}
__device__ __forceinline__ unsigned int pk2(float a, float b) {
  return (unsigned int)f2b(a) | ((unsigned int)f2b(b) << 16);
}

union U8 { uint4 v; unsigned short s[8]; };

// async global->LDS, 16B per lane, dest = wave-uniform base + lane*16
__device__ __forceinline__ void ldsload16(const unsigned short* g, unsigned short* l) {
  __builtin_amdgcn_global_load_lds(
      (const __attribute__((address_space(1))) unsigned int*)g,
      (__attribute__((address_space(3))) unsigned int*)l, 16, 0, 0);
}

// swizzled frag read: rows are 64 shorts (128B) unpadded; 16B unit index is
// XORed with (row&7) so 16 consecutive rows spread over all banks.
__device__ __forceinline__ bf16x8 frag_ld(const unsigned short* base, int row, int ks, int quad) {
  const int unit = (ks * 4 + quad) ^ (row & 7);
  return *(const bf16x8*)(base + row * 64 + unit * 8);
}

// -------- prep: all casts/transposes fused into one launch --------
// sections: [0,2048) x-cast | [2048,2114) Er cast+pad | [2114,2882) W_attn^T
//           [2882,3138) W_proj^T
__global__ __launch_bounds__(256) void prep(
    const float* __restrict__ x, const float* __restrict__ Wa,
    const float* __restrict__ Wp, const float* __restrict__ Er,
    unsigned short* __restrict__ xb, unsigned short* __restrict__ wabT,
    unsigned short* __restrict__ wpbT, unsigned short* __restrict__ erb) {
  __shared__ unsigned short tt[64][65];
  int gb = blockIdx.x;
  if (gb < 2048) {  // x: 524288 uint4 elems
    int i = gb * 256 + threadIdx.x;
    const float4* s4 = (const float4*)x;
    float4 a = s4[i * 2], b = s4[i * 2 + 1];
    U8 u;
    u.s[0] = f2b(a.x); u.s[1] = f2b(a.y); u.s[2] = f2b(a.z); u.s[3] = f2b(a.w);
    u.s[4] = f2b(b.x); u.s[5] = f2b(b.y); u.s[6] = f2b(b.z); u.s[7] = f2b(b.w);
    ((uint4*)xb)[i] = u.v;
    return;
  }
  gb -= 2048;
  if (gb < 66) {  // Er: 16896 8-elem groups; groups >= 16384 are zero pad
    int i = gb * 256 + threadIdx.x;
    if (i < 16384) {
      const float4* s4 = (const float4*)Er;
      float4 a = s4[i * 2], b = s4[i * 2 + 1];
      U8 u;
      u.s[0] = f2b(a.x); u.s[1] = f2b(a.y); u.s[2] = f2b(a.z); u.s[3] = f2b(a.w);
      u.s[4] = f2b(b.x); u.s[5] = f2b(b.y); u.s[6] = f2b(b.z); u.s[7] = f2b(b.w);
      ((uint4*)erb)[i] = u.v;
    } else {
      ((uint4*)erb)[i] = make_uint4(0u, 0u, 0u, 0u);
    }
    return;
  }
  gb -= 66;
  const float* src;
  unsigned short* dst;
  int N, nbx;
  if (gb < 768) { src = Wa; dst = wabT; N = 3072; nbx = 48; }
  else { gb -= 768; src = Wp; dst = wpbT; N = 1024; nbx = 16; }
  const int n0 = (gb % nbx) * 64, k0 = (gb / nbx) * 64;
  const int c = threadIdx.x & 63, r0 = threadIdx.x >> 6;
#pragma unroll
  for (int i = 0; i < 16; i++) {
    int r = r0 * 16 + i;
    tt[r][c] = f2b(src[(size_t)(k0 + r) * N + n0 + c]);
  }
  __syncthreads();
  const int n = threadIdx.x >> 2, ks = (threadIdx.x & 3) * 16;
  U8 u0, u1;
#pragma unroll
  for (int j = 0; j < 8; j++) {
    u0.s[j] = tt[ks + j][n];
    u1.s[j] = tt[ks + 8 + j][n];
  }
  unsigned short* d = dst + (size_t)(n0 + n) * 1024 + k0 + ks;
  *(uint4*)d = u0.v;
  *(uint4*)(d + 8) = u1.v;
}

// -------- QKV GEMM: C = A(MxK)*B + bias, Bt = B^T row-major; scatter q/k/v.
// q pre-scaled by QSCALE; V stored TRANSPOSED per head: (b,h,d,l).
__global__ __launch_bounds__(256, 3) void gemm_qkv(
    const unsigned short* __restrict__ A, const unsigned short* __restrict__ Bt,
    const float* __restrict__ bias, unsigned short* __restrict__ qbuf,
    unsigned short* __restrict__ kbuf, unsigned short* __restrict__ vbufT,
    int M, int N, int K) {
  __shared__ unsigned short As[128 * 64];
  __shared__ unsigned short Bs[128 * 64];
  const int tid = threadIdx.x, lane = tid & 63, w = tid >> 6;
  const int wm = w >> 1, wn = w & 1, quad = lane >> 4, lc = lane & 15;
  const int bm = blockIdx.y, bn = blockIdx.x;
  const int l8 = lane >> 3, u8 = ((lane & 7) ^ l8) * 8;
  const unsigned short* Ab = A + (size_t)bm * 128 * K;
  const unsigned short* Bb = Bt + (size_t)bn * 128 * K;

  f32x4 z4 = {0.f, 0.f, 0.f, 0.f};
  f32x4 acc[4][4];
#pragma unroll
  for (int mb = 0; mb < 4; mb++)
#pragma unroll
    for (int nb = 0; nb < 4; nb++) acc[mb][nb] = z4;

  for (int kk = 0; kk < K; kk += 64) {
    if (kk) __syncthreads();
#pragma unroll
    for (int i = 0; i < 4; i++) {
      int ch = w * 4 + i;
      ldsload16(Ab + (size_t)(ch * 8 + l8) * K + kk + u8, &As[ch * 512]);
      ldsload16(Bb + (size_t)(ch * 8 + l8) * K + kk + u8, &Bs[ch * 512]);
    }
    __syncthreads();
#pragma unroll
    for (int ks = 0; ks < 2; ks++) {
      bf16x8 af[4], bfv[4];
#pragma unroll
      for (int mb = 0; mb < 4; mb++) af[mb] = frag_ld(As, wm * 64 + mb * 16 + lc, ks, quad);
#pragma unroll
      for (int nb = 0; nb < 4; nb++) bfv[nb] = frag_ld(Bs, wn * 64 + nb * 16 + lc, ks, quad);
#pragma unroll
      for (int mb = 0; mb < 4; mb++)
#pragma unroll
        for (int nb = 0; nb < 4; nb++)
          acc[mb][nb] = __builtin_amdgcn_mfma_f32_16x16x32_bf16(af[mb], bfv[nb],
                                                               acc[mb][nb], 0, 0, 0);
    }
  }

#pragma unroll
  for (int nb = 0; nb < 4; nb++) {
    const int n = bn * 128 + wn * 64 + nb * 16 + lc;
    const float bv = bias[n];
    const int which = n >> 10;
    const int rem = n & 1023;
    const int h = rem >> 6, d = rem & 63;
    const float sc = which == 0 ? QSCALE : 1.0f;
#pragma unroll
    for (int mb = 0; mb < 4; mb++) {
#pragma unroll
      for (int reg = 0; reg < 4; reg++) {
        const int m = bm * 128 + wm * 64 + mb * 16 + quad * 4 + reg;
        const int b = m >> 11, l = m & 2047;
        float val = (acc[mb][nb][reg] + bv) * sc;
        if (which == 0)
          qbuf[((size_t)(b * NHEAD + h) * L_SEQ + l) * HS + d] = f2b(val);
        else if (which == 1)
          kbuf[((size_t)(b * NHEAD + h) * L_SEQ + l) * HS + d] = f2b(val);
        else
          vbufT[((size_t)(b * NHEAD + h) * HS + d) * L_SEQ + l] = f2b(val);
      }
    }
  }
}

// -------- proj GEMM: 128Mx64N tile -> 512 blocks (2/CU), f32 out --------
__global__ __launch_bounds__(256, 2) void gemm_proj(
    const unsigned short* __restrict__ A, const unsigned short* __restrict__ Bt,
    const float* __restrict__ bias, float* __restrict__ out, int M, int N, int K) {
  __shared__ unsigned short As[128 * 64];
  __shared__ unsigned short Bs[64 * 64];
  const int tid = threadIdx.x, lane = tid & 63, w = tid >> 6;
  const int quad = lane >> 4, lc = lane & 15;
  const int bm = blockIdx.y, bn = blockIdx.x;
  const int l8 = lane >> 3, u8 = ((lane & 7) ^ l8) * 8;
  const unsigned short* Ab = A + (size_t)bm * 128 * K;
  const unsigned short* Bb = Bt + (size_t)bn * 64 * K;

  f32x4 z4 = {0.f, 0.f, 0.f, 0.f};
  f32x4 acc[2][4];
#pragma unroll
  for (int mb = 0; mb < 2; mb++)
#pragma unroll
    for (int nb = 0; nb < 4; nb++) acc[mb][nb] = z4;

  for (int kk = 0; kk < K; kk += 64) {
    if (kk) __syncthreads();
#pragma unroll
    for (int i = 0; i < 4; i++) {
      int ch = w * 4 + i;
      ldsload16(Ab + (size_t)(ch * 8 + l8) * K + kk + u8, &As[ch * 512]);
    }
#pragma unroll
    for (int i = 0; i < 2; i++) {
      int ch = w * 2 + i;
      ldsload16(Bb + (size_t)(ch * 8 + l8) * K + kk + u8, &Bs[ch * 512]);
    }
    __syncthreads();
#pragma unroll
    for (int ks = 0; ks < 2; ks++) {
      bf16x8 af[2], bfv[4];
#pragma unroll
      for (int mb = 0; mb < 2; mb++) af[mb] = frag_ld(As, w * 32 + mb * 16 + lc, ks, quad);
#pragma unroll
      for (int nb = 0; nb < 4; nb++) bfv[nb] = frag_ld(Bs, nb * 16 + lc, ks, quad);
#pragma unroll
      for (int mb = 0; mb < 2; mb++)
#pragma unroll
        for (int nb = 0; nb < 4; nb++)
          acc[mb][nb] = __builtin_amdgcn_mfma_f32_16x16x32_bf16(af[mb], bfv[nb],
                                                               acc[mb][nb], 0, 0, 0);
    }
  }

#pragma unroll
  for (int nb = 0; nb < 4; nb++) {
    const int n = bn * 64 + nb * 16 + lc;
    const float bv = bias[n];
#pragma unroll
    for (int mb = 0; mb < 2; mb++) {
#pragma unroll
      for (int reg = 0; reg < 4; reg++) {
        const int m = bm * 128 + w * 32 + mb * 16 + quad * 4 + reg;
        out[(size_t)m * N + n] = acc[mb][nb][reg] + bv;
      }
    }
  }
}

// -------- flash attention with relative positions, transposed-S --------
// Srel[q,k] = q . Er[L-1-q+k] (k<=q). Wave owns 16 q rows. LDS-staged K, V^T
// (pre-transposed in global), Er band via global_load_lds. NO online softmax:
// scores are bounded (~15 in exp2 domain), so p=exp2(s+t) accumulates
// directly; one sum reduction at the end. LDS 54272B -> 3 blocks/CU.
//
// SPLIT-K (this round): the associativity of the no-online-softmax form means
// a k-chunk's (O, psum) partials combine by plain addition. Chunks of 8
// k-tiles -> critical path 32 -> 8 serial iterations, grid 1024 -> 2560
// equal-work blocks (fixes the causal-tail: previously the 32 longest blocks
// ran 32 serial iters on 32 CUs while 224 idled -> Occupancy 19%, MfmaUtil 16%).
// blockIdx.y -> (qt, chunk): j=0: y in [0,32) qt=31-y; j=1: [32,56) qt=63-y;
// j=2: [56,72) qt=87-y; j=3: [72,80) qt=103-y. qt<8 (single chunk) finalizes
// in-place; qt>=8 writes f32 partials reduced by flash_reduce.
__global__ __launch_bounds__(256, 3) void flash_attn_rel(
    const unsigned short* __restrict__ qb, const unsigned short* __restrict__ kb,
    const unsigned short* __restrict__ vbT, const unsigned short* __restrict__ erb,
    unsigned short* __restrict__ yb, float* __restrict__ pO,
    float* __restrict__ ppsum, const int use_split) {
  __shared__ unsigned short Ks[64 * 64];   // K tile, swizzled rows
  __shared__ unsigned short Vt[64 * 64];   // V^T tile, swizzled rows
  __shared__ unsigned short Es[128 * 64];  // Er band; reused as Yt[64][72] epilogue
  __shared__ float Twf[4][16 * 84];        // per-wave T^T f32 [q][e]; P overlaps

  const int tid = threadIdx.x, lane = tid & 63, w = tid >> 6;
  const int quad = lane >> 4, lc = lane & 15;
  const int bh = blockIdx.x;
  const int b = bh >> 4, h = bh & 15;
  const int y = blockIdx.y;
  int qt, jc;
  if (!use_split)      { qt = 31 - y;  jc = 0; }
  else if (y < 32)     { qt = 31 - y;  jc = 0; }
  else if (y < 56)     { qt = 63 - y;  jc = 1; }
  else if (y < 72)     { qt = 87 - y;  jc = 2; }
  else                 { qt = 103 - y; jc = 3; }
  const int q0 = qt * 64;
  const int kbeg = use_split ? (jc << 9) : 0;
  const int kend = use_split ? min(kbeg + 512, q0 + 64) : (q0 + 64);
  const int qg0 = q0 + w * 16;  // wave's first q row
  const size_t hoff = (size_t)bh * L_SEQ * HS;
  float* TwfW = Twf[w];
  unsigned short* TwpW = (unsigned short*)TwfW;  // P region overlaps T region
  const int l8 = lane >> 3, u8 = ((lane & 7) ^ l8) * 8;
  const f32x4 z4 = {0.f, 0.f, 0.f, 0.f};

  // Q fragment (q pre-scaled by QSCALE at QKV epilogue)
  bf16x8 qf[2];
  {
    const unsigned short* qrow = qb + hoff + (size_t)(qg0 + lc) * HS;
    qf[0] = *(const bf16x8*)(qrow + quad * 8);
    qf[1] = *(const bf16x8*)(qrow + 32 + quad * 8);
  }
  f32x4 Oacc[4];
#pragma unroll
  for (int db = 0; db < 4; db++) Oacc[db] = z4;
  float psum_acc = 0.0f;

  const unsigned short* kgb = kb + hoff;
  const unsigned short* vgbT = vbT + (size_t)bh * HS * L_SEQ;
  const int ebw = 48 - w * 16;  // wave's band start within Es

  for (int k0 = kbeg; k0 < kend; k0 += 64) {
    __syncthreads();  // prior-iter LDS reads complete
    // --- stage K, V^T, Er band (all global_load_lds width-16, swizzled) ---
#pragma unroll
    for (int i = 0; i < 2; i++) {
      int ch = w * 2 + i;
      ldsload16(kgb + (size_t)(k0 + ch * 8 + l8) * HS + u8, &Ks[ch * 512]);
      ldsload16(vgbT + (size_t)(ch * 8 + l8) * L_SEQ + k0 + u8, &Vt[ch * 512]);
    }
    const int e0 = (L_SEQ - 64) - q0 + k0;  // >= 0; max row e0+127 <= L+63 (padded)
#pragma unroll
    for (int i = 0; i < 4; i++) {
      int ch = w * 4 + i;
      ldsload16(erb + (size_t)(e0 + ch * 8 + l8) * HS + u8, &Es[ch * 512]);
    }
    __syncthreads();

    // --- S^T = K Q^T (4 blocks), T^T = ErBand Q^T (5 blocks) ---
    f32x4 sacc[4], tacc[5];
#pragma unroll
    for (int i = 0; i < 4; i++) sacc[i] = z4;
#pragma unroll
    for (int i = 0; i < 5; i++) tacc[i] = z4;
#pragma unroll
    for (int ks = 0; ks < 2; ks++) {
#pragma unroll
      for (int kbi = 0; kbi < 4; kbi++) {
        bf16x8 a = frag_ld(Ks, kbi * 16 + lc, ks, quad);
        sacc[kbi] = __builtin_amdgcn_mfma_f32_16x16x32_bf16(a, qf[ks], sacc[kbi], 0, 0, 0);
      }
#pragma unroll
      for (int eb = 0; eb < 5; eb++) {
        bf16x8 a = frag_ld(Es, ebw + eb * 16 + lc, ks, quad);
        tacc[eb] = __builtin_amdgcn_mfma_f32_16x16x32_bf16(a, qf[ks], tacc[eb], 0, 0, 0);
      }
    }
    // T^T -> wave-private LDS f32: TwfW[q=lc][e], e = eb*16+quad*4+reg
#pragma unroll
    for (int eb = 0; eb < 5; eb++)
      *(f32x4*)&TwfW[lc * 84 + eb * 16 + quad * 4] = tacc[eb];
    asm volatile("" ::: "memory");

    // --- p = exp2(s + t); no max subtraction (scores bounded ~15) ---
    float p[4][4], ps = 0.0f;
    const int tbase = lc * 84 + (15 - lc);
    if (k0 == q0) {
      const int qrow = w * 16 + lc;
#pragma unroll
      for (int kbi = 0; kbi < 4; kbi++)
#pragma unroll
        for (int reg = 0; reg < 4; reg++) {
          const int kk = kbi * 16 + quad * 4 + reg;
          float t = TwfW[tbase + kk];
          float v = (kk > qrow) ? -1e30f : (sacc[kbi][reg] + t);
          p[kbi][reg] = fexp2(v);
          ps += p[kbi][reg];
        }
    } else {
#pragma unroll
      for (int kbi = 0; kbi < 4; kbi++)
#pragma unroll
        for (int reg = 0; reg < 4; reg++) {
          float t = TwfW[tbase + kbi * 16 + quad * 4 + reg];
          p[kbi][reg] = fexp2(sacc[kbi][reg] + t);
          ps += p[kbi][reg];
        }
    }
    psum_acc += ps;
    // P -> wave-private LDS bf16 (overlaps T region; program order safe)
#pragma unroll
    for (int kbi = 0; kbi < 4; kbi++) {
      uint2 pk;
      pk.x = pk2(p[kbi][0], p[kbi][1]);
      pk.y = pk2(p[kbi][2], p[kbi][3]);
      const int k = kbi * 16 + quad * 4;
      *(uint2*)&TwpW[lc * 64 + (((k >> 3) ^ (lc & 7)) << 3) + (k & 7)] = pk;
    }
    asm volatile("" ::: "memory");

    // --- O^T += V^T P^T ---
#pragma unroll
    for (int ks = 0; ks < 2; ks++) {
      bf16x8 pf = frag_ld(TwpW, lc, ks, quad);
#pragma unroll
      for (int db = 0; db < 4; db++) {
        bf16x8 av = frag_ld(Vt, db * 16 + lc, ks, quad);
        Oacc[db] = __builtin_amdgcn_mfma_f32_16x16x32_bf16(av, pf, Oacc[db], 0, 0, 0);
      }
    }
  }

  // --- partial-sum reduction across quads: full (chunk) sum for q=qg0+lc ---
  psum_acc += __shfl_xor(psum_acc, 16, 64);
  psum_acc += __shfl_xor(psum_acc, 32, 64);

  if (use_split && qt >= 8) {
    // --- split path: write f32 partials (O^T regs -> [q][d] layout) ---
    const size_t pbase = ((size_t)bh * 24 + (qt - 8)) * 4 + jc;
    float* po = pO + pbase * 4096 + (size_t)(w * 16 + lc) * 64 + quad * 4;
#pragma unroll
    for (int db = 0; db < 4; db++) *(f32x4*)(po + db * 16) = Oacc[db];
    if (quad == 0) ppsum[pbase * 64 + w * 16 + lane] = psum_acc;
    return;
  }

  const float inv = 1.0f / psum_acc;

  // --- epilogue: O^T/l -> LDS transpose -> coalesced store ---
  __syncthreads();
  unsigned short* Yt = Es;  // reuse as [64][72]
#pragma unroll
  for (int db = 0; db < 4; db++) {
    uint2 pk;
    pk.x = pk2(Oacc[db][0] * inv, Oacc[db][1] * inv);
    pk.y = pk2(Oacc[db][2] * inv, Oacc[db][3] * inv);
    *(uint2*)&Yt[(w * 16 + lc) * 72 + db * 16 + quad * 4] = pk;
  }
  __syncthreads();
  {
    const int r = tid >> 2, seg = (tid & 3) * 16;
    uint4 a0 = *(const uint4*)&Yt[r * 72 + seg];
    uint4 a1 = *(const uint4*)&Yt[r * 72 + seg + 8];
    unsigned short* d = yb + (size_t)((size_t)b * L_SEQ + q0 + r) * D_MODEL + h * HS + seg;
    *(uint4*)d = a0;
    *(uint4*)(d + 8) = a1;
  }
}

// -------- reduce split-K partials: sum chunks, normalize, emit ybuf bf16 ---
// grid (32 bh, 24 qy) -> qt = qy+8, nch = qt/8+1 in 2..4.
// thread t owns 16 consecutive floats: q = t>>2, dseg = (t&3)*16 ->
// wave reads 4KB contiguous per chunk (fully coalesced; partials L2/L3-hot).
__global__ __launch_bounds__(256) void flash_reduce(
    const float* __restrict__ pO, const float* __restrict__ ppsum,
    unsigned short* __restrict__ yb) {
  const int bh = blockIdx.x, qy = blockIdx.y;
  const int qt = qy + 8;
  const int nch = (qt >> 3) + 1;
  const int b = bh >> 4, h = bh & 15;
  const int q0 = qt * 64;
  const int t = threadIdx.x;
  const int q = t >> 2, dseg = (t & 3) * 16;
  const size_t pbase = ((size_t)bh * 24 + qy) * 4;
  const float* p0 = pO + pbase * 4096 + (size_t)q * 64 + dseg;
  f32x4 a0 = *(const f32x4*)(p0);
  f32x4 a1 = *(const f32x4*)(p0 + 4);
  f32x4 a2 = *(const f32x4*)(p0 + 8);
  f32x4 a3 = *(const f32x4*)(p0 + 12);
  float ps = ppsum[pbase * 64 + q];
  for (int jj = 1; jj < nch; jj++) {
    const float* pj = p0 + (size_t)jj * 4096;
    a0 += *(const f32x4*)(pj);
    a1 += *(const f32x4*)(pj + 4);
    a2 += *(const f32x4*)(pj + 8);
    a3 += *(const f32x4*)(pj + 12);
    ps += ppsum[pbase * 64 + (size_t)jj * 64 + q];
  }
  const float inv = 1.0f / ps;
  U8 u0, u1;
#pragma unroll
  for (int i = 0; i < 4; i++) {
    u0.s[i]     = f2b(a0[i] * inv);
    u0.s[4 + i] = f2b(a1[i] * inv);
    u1.s[i]     = f2b(a2[i] * inv);
    u1.s[4 + i] = f2b(a3[i] * inv);
  }
  unsigned short* d = yb + ((size_t)b * L_SEQ + q0 + q) * D_MODEL + h * HS + dseg;
  *(uint4*)d = u0.v;
  *(uint4*)(d + 8) = u1.v;
}

extern "C" void kernel_launch(void* const* d_in, const int* in_sizes, int n_in,
                              void* d_out, int out_size, void* d_ws, size_t ws_size,
                              hipStream_t stream) {
  const float* x = (const float*)d_in[0];
  const float* W_attn = (const float*)d_in[1];
  const float* b_attn = (const float*)d_in[2];
  const float* W_proj = (const float*)d_in[3];
  const float* b_proj = (const float*)d_in[4];
  const float* Er = (const float*)d_in[5];
  float* out = (float*)d_out;

  const int n_x = B_BATCH * L_SEQ * D_MODEL;        // 4,194,304
  const int n_wa = D_MODEL * 3 * D_MODEL;           // 3,145,728
  const int n_wp = D_MODEL * D_MODEL;               // 1,048,576
  const int n_er_pad = (L_SEQ + 64) * HS;           // 135,168 (64 zero rows)
  const int n_head = B_BATCH * NHEAD * L_SEQ * HS;  // 4,194,304

  unsigned short* xb = (unsigned short*)d_ws;
  unsigned short* wabT = xb + n_x;     // W_attn^T (3072 x 1024) bf16
  unsigned short* wpbT = wabT + n_wa;  // W_proj^T (1024 x 1024) bf16
  unsigned short* erb = wpbT + n_wp;
  unsigned short* qbuf = erb + n_er_pad;
  unsigned short* kbuf = qbuf + n_head;
  unsigned short* vbufT = kbuf + n_head;  // V^T per head: (b,h,d,l)
  unsigned short* ybuf = vbufT + n_head;  // (B*L, D) bf16

  // split-K partials: pO [32 bh][24 qy][4 ch][64 q][64 d] f32, ppsum [...][64 q]
  const size_t n_pO = (size_t)32 * 24 * 4 * 64 * 64;  // 12,582,912 floats
  const size_t n_ppsum = (size_t)32 * 24 * 4 * 64;    //    196,608 floats
  float* pO = (float*)(ybuf + n_x);
  float* ppsum = pO + n_pO;
  const size_t base_bytes = ((size_t)ybuf + (size_t)n_x * 2) - (size_t)d_ws;
  const size_t need = base_bytes + (n_pO + n_ppsum) * sizeof(float);
  const int use_split = (ws_size >= need) ? 1 : 0;  // fallback = old schedule

  prep<<<3138, 256, 0, stream>>>(x, W_attn, W_proj, Er, xb, wabT, wpbT, erb);

  gemm_qkv<<<dim3(24, 32), 256, 0, stream>>>(xb, wabT, b_attn, qbuf, kbuf, vbufT,
                                             B_BATCH * L_SEQ, 3 * D_MODEL, D_MODEL);

  flash_attn_rel<<<dim3(B_BATCH * NHEAD, use_split ? 80 : 32), 256, 0, stream>>>(
      qbuf, kbuf, vbufT, erb, ybuf, pO, ppsum, use_split);

  if (use_split)
    flash_reduce<<<dim3(B_BATCH * NHEAD, 24), 256, 0, stream>>>(pO, ppsum, ybuf);

  gemm_proj<<<dim3(16, 32), 256, 0, stream>>>(ybuf, wpbT, b_proj, out,
                                              B_BATCH * L_SEQ, D_MODEL, D_MODEL);
}

// Round 2
// 216.651 us; speedup vs baseline: 1.0294x; 1.0294x over previous
//
#include <hip/hip_runtime.h>
#include <stdint.h>

#define L_SEQ 2048
#define D_MODEL 1024
#define NHEAD 16
#define HS 64
#define B_BATCH 2
// 1/sqrt(64) * log2(e), folded into q at QKV epilogue (softmax in exp2 domain)
#define QSCALE 0.1803368801111243f

typedef __bf16 bf16x8 __attribute__((ext_vector_type(8)));
typedef float f32x4 __attribute__((ext_vector_type(4)));

__device__ __forceinline__ float fexp2(float x) {
  return __builtin_amdgcn_exp2f(x);  // v_exp_f32: D = 2^S0
}

__device__ __forceinline__ unsigned short f2b(float f) {
  unsigned int u = __float_as_uint(f);
  u += 0x7fffu + ((u >> 16) & 1u);
  return (unsigned short)(u >> 16);
}
__device__ __forceinline__ unsigned int pk2(float a, float b) {
  return (unsigned int)f2b(a) | ((unsigned int)f2b(b) << 16);
}

union U8 { uint4 v; unsigned short s[8]; };

// async global->LDS, 16B per lane, dest = wave-uniform base + lane*16
__device__ __forceinline__ void ldsload16(const unsigned short* g, unsigned short* l) {
  __builtin_amdgcn_global_load_lds(
      (const __attribute__((address_space(1))) unsigned int*)g,
      (__attribute__((address_space(3))) unsigned int*)l, 16, 0, 0);
}

// swizzled frag read: rows are 64 shorts (128B) unpadded; 16B unit index is
// XORed with (row&7) so 16 consecutive rows spread over all banks.
__device__ __forceinline__ bf16x8 frag_ld(const unsigned short* base, int row, int ks, int quad) {
  const int unit = (ks * 4 + quad) ^ (row & 7);
  return *(const bf16x8*)(base + row * 64 + unit * 8);
}

// -------- prep: all casts/transposes fused into one launch --------
// sections: [0,2048) x-cast | [2048,2116) Er cast+pad | [2116,2884) W_attn^T
//           [2884,3140) W_proj^T
__global__ __launch_bounds__(256) void prep(
    const float* __restrict__ x, const float* __restrict__ Wa,
    const float* __restrict__ Wp, const float* __restrict__ Er,
    unsigned short* __restrict__ xb, unsigned short* __restrict__ wabT,
    unsigned short* __restrict__ wpbT, unsigned short* __restrict__ erb) {
  __shared__ unsigned short tt[64][65];
  int gb = blockIdx.x;
  if (gb < 2048) {  // x: 524288 uint4 elems
    int i = gb * 256 + threadIdx.x;
    const float4* s4 = (const float4*)x;
    float4 a = s4[i * 2], b = s4[i * 2 + 1];
    U8 u;
    u.s[0] = f2b(a.x); u.s[1] = f2b(a.y); u.s[2] = f2b(a.z); u.s[3] = f2b(a.w);
    u.s[4] = f2b(b.x); u.s[5] = f2b(b.y); u.s[6] = f2b(b.z); u.s[7] = f2b(b.w);
    ((uint4*)xb)[i] = u.v;
    return;
  }
  gb -= 2048;
  if (gb < 68) {  // Er: 17408 8-elem groups; groups >= 16384 are zero pad (128 pad rows)
    int i = gb * 256 + threadIdx.x;
    if (i < 16384) {
      const float4* s4 = (const float4*)Er;
      float4 a = s4[i * 2], b = s4[i * 2 + 1];
      U8 u;
      u.s[0] = f2b(a.x); u.s[1] = f2b(a.y); u.s[2] = f2b(a.z); u.s[3] = f2b(a.w);
      u.s[4] = f2b(b.x); u.s[5] = f2b(b.y); u.s[6] = f2b(b.z); u.s[7] = f2b(b.w);
      ((uint4*)erb)[i] = u.v;
    } else {
      ((uint4*)erb)[i] = make_uint4(0u, 0u, 0u, 0u);
    }
    return;
  }
  gb -= 68;
  const float* src;
  unsigned short* dst;
  int N, nbx;
  if (gb < 768) { src = Wa; dst = wabT; N = 3072; nbx = 48; }
  else { gb -= 768; src = Wp; dst = wpbT; N = 1024; nbx = 16; }
  const int n0 = (gb % nbx) * 64, k0 = (gb / nbx) * 64;
  const int c = threadIdx.x & 63, r0 = threadIdx.x >> 6;
#pragma unroll
  for (int i = 0; i < 16; i++) {
    int r = r0 * 16 + i;
    tt[r][c] = f2b(src[(size_t)(k0 + r) * N + n0 + c]);
  }
  __syncthreads();
  const int n = threadIdx.x >> 2, ks = (threadIdx.x & 3) * 16;
  U8 u0, u1;
#pragma unroll
  for (int j = 0; j < 8; j++) {
    u0.s[j] = tt[ks + j][n];
    u1.s[j] = tt[ks + 8 + j][n];
  }
  unsigned short* d = dst + (size_t)(n0 + n) * 1024 + k0 + ks;
  *(uint4*)d = u0.v;
  *(uint4*)(d + 8) = u1.v;
}

// -------- QKV GEMM: C = A(MxK)*B + bias, Bt = B^T row-major; scatter q/k/v.
// q pre-scaled by QSCALE; V stored TRANSPOSED per head: (b,h,d,l).
__global__ __launch_bounds__(256, 3) void gemm_qkv(
    const unsigned short* __restrict__ A, const unsigned short* __restrict__ Bt,
    const float* __restrict__ bias, unsigned short* __restrict__ qbuf,
    unsigned short* __restrict__ kbuf, unsigned short* __restrict__ vbufT,
    int M, int N, int K) {
  __shared__ unsigned short As[128 * 64];
  __shared__ unsigned short Bs[128 * 64];
  const int tid = threadIdx.x, lane = tid & 63, w = tid >> 6;
  const int wm = w >> 1, wn = w & 1, quad = lane >> 4, lc = lane & 15;
  const int bm = blockIdx.y, bn = blockIdx.x;
  const int l8 = lane >> 3, u8 = ((lane & 7) ^ l8) * 8;
  const unsigned short* Ab = A + (size_t)bm * 128 * K;
  const unsigned short* Bb = Bt + (size_t)bn * 128 * K;

  f32x4 z4 = {0.f, 0.f, 0.f, 0.f};
  f32x4 acc[4][4];
#pragma unroll
  for (int mb = 0; mb < 4; mb++)
#pragma unroll
    for (int nb = 0; nb < 4; nb++) acc[mb][nb] = z4;

  for (int kk = 0; kk < K; kk += 64) {
    if (kk) __syncthreads();
#pragma unroll
    for (int i = 0; i < 4; i++) {
      int ch = w * 4 + i;
      ldsload16(Ab + (size_t)(ch * 8 + l8) * K + kk + u8, &As[ch * 512]);
      ldsload16(Bb + (size_t)(ch * 8 + l8) * K + kk + u8, &Bs[ch * 512]);
    }
    __syncthreads();
#pragma unroll
    for (int ks = 0; ks < 2; ks++) {
      bf16x8 af[4], bfv[4];
#pragma unroll
      for (int mb = 0; mb < 4; mb++) af[mb] = frag_ld(As, wm * 64 + mb * 16 + lc, ks, quad);
#pragma unroll
      for (int nb = 0; nb < 4; nb++) bfv[nb] = frag_ld(Bs, wn * 64 + nb * 16 + lc, ks, quad);
#pragma unroll
      for (int mb = 0; mb < 4; mb++)
#pragma unroll
        for (int nb = 0; nb < 4; nb++)
          acc[mb][nb] = __builtin_amdgcn_mfma_f32_16x16x32_bf16(af[mb], bfv[nb],
                                                               acc[mb][nb], 0, 0, 0);
    }
  }

#pragma unroll
  for (int nb = 0; nb < 4; nb++) {
    const int n = bn * 128 + wn * 64 + nb * 16 + lc;
    const float bv = bias[n];
    const int which = n >> 10;
    const int rem = n & 1023;
    const int h = rem >> 6, d = rem & 63;
    const float sc = which == 0 ? QSCALE : 1.0f;
#pragma unroll
    for (int mb = 0; mb < 4; mb++) {
#pragma unroll
      for (int reg = 0; reg < 4; reg++) {
        const int m = bm * 128 + wm * 64 + mb * 16 + quad * 4 + reg;
        const int b = m >> 11, l = m & 2047;
        float val = (acc[mb][nb][reg] + bv) * sc;
        if (which == 0)
          qbuf[((size_t)(b * NHEAD + h) * L_SEQ + l) * HS + d] = f2b(val);
        else if (which == 1)
          kbuf[((size_t)(b * NHEAD + h) * L_SEQ + l) * HS + d] = f2b(val);
        else
          vbufT[((size_t)(b * NHEAD + h) * HS + d) * L_SEQ + l] = f2b(val);
      }
    }
  }
}

// -------- proj GEMM: 128Mx64N tile -> 512 blocks (2/CU), f32 out --------
__global__ __launch_bounds__(256, 2) void gemm_proj(
    const unsigned short* __restrict__ A, const unsigned short* __restrict__ Bt,
    const float* __restrict__ bias, float* __restrict__ out, int M, int N, int K) {
  __shared__ unsigned short As[128 * 64];
  __shared__ unsigned short Bs[64 * 64];
  const int tid = threadIdx.x, lane = tid & 63, w = tid >> 6;
  const int quad = lane >> 4, lc = lane & 15;
  const int bm = blockIdx.y, bn = blockIdx.x;
  const int l8 = lane >> 3, u8 = ((lane & 7) ^ l8) * 8;
  const unsigned short* Ab = A + (size_t)bm * 128 * K;
  const unsigned short* Bb = Bt + (size_t)bn * 64 * K;

  f32x4 z4 = {0.f, 0.f, 0.f, 0.f};
  f32x4 acc[2][4];
#pragma unroll
  for (int mb = 0; mb < 2; mb++)
#pragma unroll
    for (int nb = 0; nb < 4; nb++) acc[mb][nb] = z4;

  for (int kk = 0; kk < K; kk += 64) {
    if (kk) __syncthreads();
#pragma unroll
    for (int i = 0; i < 4; i++) {
      int ch = w * 4 + i;
      ldsload16(Ab + (size_t)(ch * 8 + l8) * K + kk + u8, &As[ch * 512]);
    }
#pragma unroll
    for (int i = 0; i < 2; i++) {
      int ch = w * 2 + i;
      ldsload16(Bb + (size_t)(ch * 8 + l8) * K + kk + u8, &Bs[ch * 512]);
    }
    __syncthreads();
#pragma unroll
    for (int ks = 0; ks < 2; ks++) {
      bf16x8 af[2], bfv[4];
#pragma unroll
      for (int mb = 0; mb < 2; mb++) af[mb] = frag_ld(As, w * 32 + mb * 16 + lc, ks, quad);
#pragma unroll
      for (int nb = 0; nb < 4; nb++) bfv[nb] = frag_ld(Bs, nb * 16 + lc, ks, quad);
#pragma unroll
      for (int mb = 0; mb < 2; mb++)
#pragma unroll
        for (int nb = 0; nb < 4; nb++)
          acc[mb][nb] = __builtin_amdgcn_mfma_f32_16x16x32_bf16(af[mb], bfv[nb],
                                                               acc[mb][nb], 0, 0, 0);
    }
  }

#pragma unroll
  for (int nb = 0; nb < 4; nb++) {
    const int n = bn * 64 + nb * 16 + lc;
    const float bv = bias[n];
#pragma unroll
    for (int mb = 0; mb < 2; mb++) {
#pragma unroll
      for (int reg = 0; reg < 4; reg++) {
        const int m = bm * 128 + w * 32 + mb * 16 + quad * 4 + reg;
        out[(size_t)m * N + n] = acc[mb][nb][reg] + bv;
      }
    }
  }
}

// -------- flash attention with relative positions, transposed-S --------
// LDS-BW-bound fix: each wave owns 32 q rows (2 Q-blocks in registers), so
// every K/V/Er fragment read from LDS feeds TWO MFMAs instead of one.
// Block tile = 128 q x 64 k, 4 waves x 32 q. Er window is a rolling 256-row
// buffer (stage only 64 new rows per k-tile; band shifts +64/iter). Softmax
// runs per-16q sub-block sequentially so the T-transpose scratch stays at
// 16x84 f32 per wave (P of qb0 parked in a side area until PV).
// Scores bounded (~15 in exp2 domain) -> no online softmax; direct p=exp2(s+t)
// accumulation, one sum reduction at the end.
// LDS: Ks 8K + Vt 8K + Es 32K + Twf 29K = 78848 B -> 2 blocks/CU.
// Tail: longest-first dispatch; y<8 -> qt=15-y (long), y>=8 -> qt=y-8 (short);
// round-robin placement pairs block c with c+256 => per-CU work ~constant.
__global__ __launch_bounds__(256, 2) void flash_attn_rel(
    const unsigned short* __restrict__ qb, const unsigned short* __restrict__ kb,
    const unsigned short* __restrict__ vbT, const unsigned short* __restrict__ erb,
    unsigned short* __restrict__ yb) {
  __shared__ unsigned short Ks[64 * 64];   // K tile, swizzled rows
  __shared__ unsigned short Vt[64 * 64];   // V^T tile, swizzled rows
  __shared__ unsigned short Es[256 * 64];  // rolling Er window; reused as Yt[128][72]
  __shared__ float Twf[4][1856];           // per wave: T area [0,1344) | P0 [1344,1856)

  const int tid = threadIdx.x, lane = tid & 63, w = tid >> 6;
  const int quad = lane >> 4, lc = lane & 15;
  const int bh = blockIdx.x;
  const int b = bh >> 4, h = bh & 15;
  const int y = (int)blockIdx.y;
  const int qt = (y < 8) ? (15 - y) : (y - 8);  // long tiles dispatched first
  const int q0 = qt * 128;
  const int qg = q0 + w * 32;  // wave's first q row (owns 32 rows)
  const size_t hoff = (size_t)bh * L_SEQ * HS;
  float* TwfW = Twf[w];
  unsigned short* TwpW1 = (unsigned short*)TwfW;            // P(qb1) overlaps T area
  unsigned short* TwpW0 = (unsigned short*)(TwfW + 1344);   // P(qb0) parked
  const int l8 = lane >> 3, u8 = ((lane & 7) ^ l8) * 8;
  const f32x4 z4 = {0.f, 0.f, 0.f, 0.f};
  const int e_anchor = L_SEQ - 128 - q0;  // e_rel = e_glob - e_anchor >= 0

  // Q fragments for both 16-row sub-blocks (q pre-scaled by QSCALE)
  bf16x8 qf[2][2];
#pragma unroll
  for (int j = 0; j < 2; j++) {
    const unsigned short* qrow = qb + hoff + (size_t)(qg + j * 16 + lc) * HS;
    qf[j][0] = *(const bf16x8*)(qrow + quad * 8);
    qf[j][1] = *(const bf16x8*)(qrow + 32 + quad * 8);
  }
  f32x4 Oacc[2][4];
#pragma unroll
  for (int j = 0; j < 2; j++)
#pragma unroll
    for (int db = 0; db < 4; db++) Oacc[j][db] = z4;
  float psum[2] = {0.0f, 0.0f};

  const unsigned short* kgb = kb + hoff;
  const unsigned short* vgbT = vbT + (size_t)bh * HS * L_SEQ;

  const int kend = q0 + 128;
  for (int k0 = 0; k0 < kend; k0 += 64) {
    __syncthreads();  // prior-iter LDS reads complete
    // --- stage K, V^T (64 rows each), Er (rolling) ---
#pragma unroll
    for (int i = 0; i < 2; i++) {
      int ch = w * 2 + i;
      ldsload16(kgb + (size_t)(k0 + ch * 8 + l8) * HS + u8, &Ks[ch * 512]);
      ldsload16(vgbT + (size_t)(ch * 8 + l8) * L_SEQ + k0 + u8, &Vt[ch * 512]);
    }
    if (k0 == 0) {
#pragma unroll
      for (int i = 0; i < 6; i++) {
        int ch = w * 6 + i;  // 24 chans -> e_rel rows [0,192)
        ldsload16(erb + (size_t)(e_anchor + ch * 8 + l8) * HS + u8, &Es[ch * 512]);
      }
    } else {
#pragma unroll
      for (int i = 0; i < 2; i++) {
        int ch = w * 2 + i;  // 8 chans -> e_rel rows [k0+128, k0+192)
        int er = k0 + 128 + ch * 8;
        ldsload16(erb + (size_t)(e_anchor + er + l8) * HS + u8, &Es[(er & 255) * 64]);
      }
    }
    __syncthreads();

    if (k0 > qg + 31) continue;  // fully masked for this wave; barrier count stays uniform

    // --- S^T = K Q^T (4x2 blocks), T^T = ErBand Q^T (6-block shared union) ---
    f32x4 sacc[2][4], tacc[2][5];
#pragma unroll
    for (int j = 0; j < 2; j++) {
#pragma unroll
      for (int i = 0; i < 4; i++) sacc[j][i] = z4;
#pragma unroll
      for (int i = 0; i < 5; i++) tacc[j][i] = z4;
    }
    const int ub = 96 - 32 * w + k0;  // union band base in e_rel (qb1 start; qb0 = +16)
#pragma unroll
    for (int ks = 0; ks < 2; ks++) {
#pragma unroll
      for (int kbi = 0; kbi < 4; kbi++) {
        bf16x8 a = frag_ld(Ks, kbi * 16 + lc, ks, quad);
        sacc[0][kbi] = __builtin_amdgcn_mfma_f32_16x16x32_bf16(a, qf[0][ks], sacc[0][kbi], 0, 0, 0);
        sacc[1][kbi] = __builtin_amdgcn_mfma_f32_16x16x32_bf16(a, qf[1][ks], sacc[1][kbi], 0, 0, 0);
      }
#pragma unroll
      for (int eb = 0; eb < 6; eb++) {
        bf16x8 a = frag_ld(Es, (ub + eb * 16 + lc) & 255, ks, quad);
        if (eb >= 1)
          tacc[0][eb - 1] = __builtin_amdgcn_mfma_f32_16x16x32_bf16(a, qf[0][ks], tacc[0][eb - 1], 0, 0, 0);
        if (eb <= 4)
          tacc[1][eb] = __builtin_amdgcn_mfma_f32_16x16x32_bf16(a, qf[1][ks], tacc[1][eb], 0, 0, 0);
      }
    }

    // --- per sub-block: T -> LDS, diagonal gather, p = exp2(s+t), pack P ---
    const int tbase = lc * 84 + (15 - lc);
#pragma unroll
    for (int j = 0; j < 2; j++) {
#pragma unroll
      for (int eb = 0; eb < 5; eb++)
        *(f32x4*)&TwfW[lc * 84 + eb * 16 + quad * 4] = tacc[j][eb];
      asm volatile("" ::: "memory");

      float p[4][4], ps = 0.0f;
      const int qgj = qg + j * 16;
      if (k0 + 63 > qgj) {  // some element masked (wave-uniform branch)
        const int qrow = qgj + lc;
#pragma unroll
        for (int kbi = 0; kbi < 4; kbi++)
#pragma unroll
          for (int reg = 0; reg < 4; reg++) {
            const int kk = kbi * 16 + quad * 4 + reg;
            float t = TwfW[tbase + kk];
            float v = (k0 + kk > qrow) ? -1e30f : (sacc[j][kbi][reg] + t);
            p[kbi][reg] = fexp2(v);
            ps += p[kbi][reg];
          }
      } else {
#pragma unroll
        for (int kbi = 0; kbi < 4; kbi++)
#pragma unroll
          for (int reg = 0; reg < 4; reg++) {
            float t = TwfW[tbase + kbi * 16 + quad * 4 + reg];
            p[kbi][reg] = fexp2(sacc[j][kbi][reg] + t);
            ps += p[kbi][reg];
          }
      }
      psum[j] += ps;
      unsigned short* Pdst = j ? TwpW1 : TwpW0;  // qb1 may overwrite T area (reads done)
#pragma unroll
      for (int kbi = 0; kbi < 4; kbi++) {
        uint2 pk;
        pk.x = pk2(p[kbi][0], p[kbi][1]);
        pk.y = pk2(p[kbi][2], p[kbi][3]);
        const int k = kbi * 16 + quad * 4;
        *(uint2*)&Pdst[lc * 64 + (((k >> 3) ^ (lc & 7)) << 3) + (k & 7)] = pk;
      }
      asm volatile("" ::: "memory");
    }

    // --- O^T += V^T P^T (V frags shared across both sub-blocks) ---
#pragma unroll
    for (int ks = 0; ks < 2; ks++) {
      bf16x8 pf0 = frag_ld(TwpW0, lc, ks, quad);
      bf16x8 pf1 = frag_ld(TwpW1, lc, ks, quad);
#pragma unroll
      for (int db = 0; db < 4; db++) {
        bf16x8 av = frag_ld(Vt, db * 16 + lc, ks, quad);
        Oacc[0][db] = __builtin_amdgcn_mfma_f32_16x16x32_bf16(av, pf0, Oacc[0][db], 0, 0, 0);
        Oacc[1][db] = __builtin_amdgcn_mfma_f32_16x16x32_bf16(av, pf1, Oacc[1][db], 0, 0, 0);
      }
    }
  }

  // --- final sum reduction: quads hold partial sums for q=qgj+lc ---
#pragma unroll
  for (int j = 0; j < 2; j++) {
    psum[j] += __shfl_xor(psum[j], 16, 64);
    psum[j] += __shfl_xor(psum[j], 32, 64);
  }

  // --- epilogue: O^T/l -> LDS transpose -> coalesced store ---
  __syncthreads();
  unsigned short* Yt = Es;  // reuse as [128][72]
#pragma unroll
  for (int j = 0; j < 2; j++) {
    const float inv = 1.0f / psum[j];
#pragma unroll
    for (int db = 0; db < 4; db++) {
      uint2 pk;
      pk.x = pk2(Oacc[j][db][0] * inv, Oacc[j][db][1] * inv);
      pk.y = pk2(Oacc[j][db][2] * inv, Oacc[j][db][3] * inv);
      *(uint2*)&Yt[(w * 32 + j * 16 + lc) * 72 + db * 16 + quad * 4] = pk;
    }
  }
  __syncthreads();
  {
    const int r = tid >> 1, seg = (tid & 1) * 32;
    uint4 a0 = *(const uint4*)&Yt[r * 72 + seg];
    uint4 a1 = *(const uint4*)&Yt[r * 72 + seg + 8];
    uint4 a2 = *(const uint4*)&Yt[r * 72 + seg + 16];
    uint4 a3 = *(const uint4*)&Yt[r * 72 + seg + 24];
    unsigned short* d = yb + (size_t)((size_t)b * L_SEQ + q0 + r) * D_MODEL + h * HS + seg;
    *(uint4*)d = a0;
    *(uint4*)(d + 8) = a1;
    *(uint4*)(d + 16) = a2;
    *(uint4*)(d + 24) = a3;
  }
}

extern "C" void kernel_launch(void* const* d_in, const int* in_sizes, int n_in,
                              void* d_out, int out_size, void* d_ws, size_t ws_size,
                              hipStream_t stream) {
  const float* x = (const float*)d_in[0];
  const float* W_attn = (const float*)d_in[1];
  const float* b_attn = (const float*)d_in[2];
  const float* W_proj = (const float*)d_in[3];
  const float* b_proj = (const float*)d_in[4];
  const float* Er = (const float*)d_in[5];
  float* out = (float*)d_out;

  const int n_x = B_BATCH * L_SEQ * D_MODEL;        // 4,194,304
  const int n_wa = D_MODEL * 3 * D_MODEL;           // 3,145,728
  const int n_wp = D_MODEL * D_MODEL;               // 1,048,576
  const int n_er_pad = (L_SEQ + 128) * HS;          // 139,264 (128 zero rows)
  const int n_head = B_BATCH * NHEAD * L_SEQ * HS;  // 4,194,304

  unsigned short* xb = (unsigned short*)d_ws;
  unsigned short* wabT = xb + n_x;     // W_attn^T (3072 x 1024) bf16
  unsigned short* wpbT = wabT + n_wa;  // W_proj^T (1024 x 1024) bf16
  unsigned short* erb = wpbT + n_wp;
  unsigned short* qbuf = erb + n_er_pad;
  unsigned short* kbuf = qbuf + n_head;
  unsigned short* vbufT = kbuf + n_head;  // V^T per head: (b,h,d,l)
  unsigned short* ybuf = vbufT + n_head;  // (B*L, D) bf16

  prep<<<3140, 256, 0, stream>>>(x, W_attn, W_proj, Er, xb, wabT, wpbT, erb);

  gemm_qkv<<<dim3(24, 32), 256, 0, stream>>>(xb, wabT, b_attn, qbuf, kbuf, vbufT,
                                             B_BATCH * L_SEQ, 3 * D_MODEL, D_MODEL);

  flash_attn_rel<<<dim3(B_BATCH * NHEAD, 16), 256, 0, stream>>>(qbuf, kbuf, vbufT,
                                                                erb, ybuf);

  gemm_proj<<<dim3(16, 32), 256, 0, stream>>>(ybuf, wpbT, b_proj, out,
                                              B_BATCH * L_SEQ, D_MODEL, D_MODEL);
}